// Round 2
// baseline (635.948 us; speedup 1.0000x reference)
//
#include <hip/hip_runtime.h>
#include <stdint.h>

typedef unsigned short u16;
typedef unsigned int   u32;

typedef __bf16 bf16x8 __attribute__((ext_vector_type(8)));
typedef float  f32x4  __attribute__((ext_vector_type(4)));

__device__ __forceinline__ float bf2f(u16 h) {
    return __uint_as_float(((u32)h) << 16);
}
__device__ __forceinline__ u16 f2bf(float f) {
    u32 u = __float_as_uint(f);
    u += 0x7FFFu + ((u >> 16) & 1u);   // RNE
    return (u16)(u >> 16);
}

#define GLOAD_LDS16(g, l)                                                     \
    __builtin_amdgcn_global_load_lds(                                         \
        (const __attribute__((address_space(1))) void*)(g),                   \
        (__attribute__((address_space(3))) void*)(l), 16, 0, 0)

// ---------------------------------------------------------------------------
// f32 -> bf16 bulk convert, 8 elems/thread
// ---------------------------------------------------------------------------
__global__ __launch_bounds__(256) void cvt_f32_bf16(const float* __restrict__ in,
                                                    u16* __restrict__ out) {
    int i = blockIdx.x * 256 + threadIdx.x;
    const float4* p = (const float4*)in + (size_t)i * 2;
    float4 a = p[0], b = p[1];
    union { u16 s[8]; uint4 v; } o;
    o.s[0] = f2bf(a.x); o.s[1] = f2bf(a.y); o.s[2] = f2bf(a.z); o.s[3] = f2bf(a.w);
    o.s[4] = f2bf(b.x); o.s[5] = f2bf(b.y); o.s[6] = f2bf(b.z); o.s[7] = f2bf(b.w);
    ((uint4*)out)[i] = o.v;
}

// ---------------------------------------------------------------------------
// Transpose+convert W[R][Cc] (f32) -> Wt[Cc][R] (bf16), dims multiple of 32
// ---------------------------------------------------------------------------
__global__ void transpose_cvt(const float* __restrict__ in, u16* __restrict__ out,
                              int R, int Cc) {
    __shared__ float tile[32][33];
    int c0 = blockIdx.x * 32, r0 = blockIdx.y * 32;
    int tx = threadIdx.x, ty = threadIdx.y;
    tile[ty][tx] = in[(size_t)(r0 + ty) * Cc + c0 + tx];
    __syncthreads();
    out[(size_t)(c0 + ty) * R + r0 + tx] = f2bf(tile[tx][ty]);
}

// ---------------------------------------------------------------------------
// C[M][N] = A[M][K] @ Bt[N][K]^T + bias[N] (+ res[M][N]); A,Bt bf16, acc f32.
// bias/res f32. Output bf16 or f32 per template. 128x128 tile, BK=32,
// 256 threads (4 waves), m97 structure. M%128==0, N%128==0, K%32==0.
// ---------------------------------------------------------------------------
template <bool OUT_F32>
__global__ __launch_bounds__(256) void gemm_bt(
    const u16* __restrict__ A, const u16* __restrict__ Bt,
    const float* __restrict__ bias, const float* __restrict__ res,
    void* __restrict__ Cout, int M, int N, int K)
{
    __shared__ __align__(16) u16 As[128 * 32];
    __shared__ __align__(16) u16 Bs[128 * 32];

    const int t    = threadIdx.x;
    const int lane = t & 63;
    const int w    = t >> 6;
    const int wm   = w >> 1, wn = w & 1;
    const int quad = lane >> 4, l16 = lane & 15;

    const size_t m0 = (size_t)blockIdx.y * 128;
    const size_t n0 = (size_t)blockIdx.x * 128;

    const u16* Ab = A + m0 * K;
    const u16* Bb = Bt + n0 * K;

    const int rA0 = t >> 2;            // 0..63
    const int cA0 = (t & 3) * 8;       // 0,8,16,24

    f32x4 acc[4][4];
    const f32x4 fzero = {0.f, 0.f, 0.f, 0.f};
#pragma unroll
    for (int i = 0; i < 4; i++)
#pragma unroll
        for (int j = 0; j < 4; j++) acc[i][j] = fzero;

    for (int k0 = 0; k0 < K; k0 += 32) {
        const u16* ga0 = Ab + (size_t)rA0 * K + k0 + cA0;
        const u16* ga1 = ga0 + (size_t)64 * K;
        const u16* gb0 = Bb + (size_t)rA0 * K + k0 + cA0;
        const u16* gb1 = gb0 + (size_t)64 * K;
        GLOAD_LDS16(ga0, As + t * 8);
        GLOAD_LDS16(ga1, As + t * 8 + 2048);
        GLOAD_LDS16(gb0, Bs + t * 8);
        GLOAD_LDS16(gb1, Bs + t * 8 + 2048);
        __syncthreads();

        bf16x8 a[4], b[4];
#pragma unroll
        for (int mi = 0; mi < 4; mi++)
            a[mi] = *(const bf16x8*)(As + (wm * 64 + mi * 16 + l16) * 32 + quad * 8);
#pragma unroll
        for (int ni = 0; ni < 4; ni++)
            b[ni] = *(const bf16x8*)(Bs + (wn * 64 + ni * 16 + l16) * 32 + quad * 8);
#pragma unroll
        for (int mi = 0; mi < 4; mi++)
#pragma unroll
            for (int ni = 0; ni < 4; ni++)
                acc[mi][ni] = __builtin_amdgcn_mfma_f32_16x16x32_bf16(
                    a[mi], b[ni], acc[mi][ni], 0, 0, 0);
        __syncthreads();
    }

#pragma unroll
    for (int ni = 0; ni < 4; ni++) {
        const size_t col = n0 + wn * 64 + ni * 16 + l16;
        const float bv = bias[col];
#pragma unroll
        for (int mi = 0; mi < 4; mi++) {
#pragma unroll
            for (int r = 0; r < 4; r++) {
                const size_t row = m0 + wm * 64 + mi * 16 + quad * 4 + r;
                float v = acc[mi][ni][r] + bv;
                if (res) v += res[row * N + col];
                if (OUT_F32) ((float*)Cout)[row * N + col] = v;
                else         ((u16*)Cout)[row * N + col]  = f2bf(v);
            }
        }
    }
}

// ---------------------------------------------------------------------------
// Attention: 1 wave per (window, head). Cyclic shift fused into the gather
// index; output written back to original token positions (window_reverse +
// roll round-trips each token to its source).
// ---------------------------------------------------------------------------
__global__ __launch_bounds__(64) void attn_kernel(
    const u16* __restrict__ qkv, const float* __restrict__ table,
    u16* __restrict__ O)
{
    __shared__ __align__(16) u16 Qs[64 * 32];   // [token][dim]
    __shared__ __align__(16) u16 Ks[64 * 32];   // [token][dim]
    __shared__ __align__(16) u16 Vts[32 * 64];  // [dim][token]
    __shared__ __align__(16) u16 Ps[64 * 72];   // [row][col], stride 72
    __shared__ float Ss[64 * 66];
    __shared__ float rinv[64];

    const int wid = blockIdx.x >> 4;
    const int h   = blockIdx.x & 15;
    const int b   = wid >> 6;
    const int wy  = (wid >> 3) & 7;
    const int wx  = wid & 7;
    const int lane = threadIdx.x;
    const int quad = lane >> 4, l16 = lane & 15;

    // ---- gather Q,K,V (49 tokens x 32 dims), zero-pad to 64 ----
    if (lane < 49) {
        int ty = lane / 7, tx = lane - ty * 7;
        int ho = wy * 7 + ty + 3; if (ho >= 56) ho -= 56;
        int wo = wx * 7 + tx + 3; if (wo >= 56) wo -= 56;
        size_t tok = ((size_t)b * 56 + ho) * 56 + wo;
        const u16* base = qkv + tok * 1536 + h * 32;
        uint4* qd = (uint4*)(Qs + lane * 32);
        const uint4* qs = (const uint4*)base;
        qd[0] = qs[0]; qd[1] = qs[1]; qd[2] = qs[2]; qd[3] = qs[3];
        uint4* kd = (uint4*)(Ks + lane * 32);
        const uint4* ks = (const uint4*)(base + 512);
        kd[0] = ks[0]; kd[1] = ks[1]; kd[2] = ks[2]; kd[3] = ks[3];
        union { uint4 u4[4]; u16 s[32]; } vb;
        const uint4* vs = (const uint4*)(base + 1024);
        vb.u4[0] = vs[0]; vb.u4[1] = vs[1]; vb.u4[2] = vs[2]; vb.u4[3] = vs[3];
#pragma unroll
        for (int d = 0; d < 32; d++) Vts[d * 64 + lane] = vb.s[d];
    } else {
        uint4 z = make_uint4(0, 0, 0, 0);
        uint4* qd = (uint4*)(Qs + lane * 32);
        qd[0] = z; qd[1] = z; qd[2] = z; qd[3] = z;
        uint4* kd = (uint4*)(Ks + lane * 32);
        kd[0] = z; kd[1] = z; kd[2] = z; kd[3] = z;
#pragma unroll
        for (int d = 0; d < 32; d++) Vts[d * 64 + lane] = 0;
    }
    __syncthreads();

    // ---- S = Q K^T  (4x4 tiles of 16x16, K=32 -> one MFMA each) ----
    {
        bf16x8 a[4], bb[4];
#pragma unroll
        for (int i = 0; i < 4; i++) {
            a[i]  = *(const bf16x8*)(Qs + (i * 16 + l16) * 32 + quad * 8);
            bb[i] = *(const bf16x8*)(Ks + (i * 16 + l16) * 32 + quad * 8);
        }
#pragma unroll
        for (int mi = 0; mi < 4; mi++) {
#pragma unroll
            for (int ni = 0; ni < 4; ni++) {
                f32x4 c = {0.f, 0.f, 0.f, 0.f};
                c = __builtin_amdgcn_mfma_f32_16x16x32_bf16(a[mi], bb[ni], c, 0, 0, 0);
#pragma unroll
                for (int r = 0; r < 4; r++)
                    Ss[(mi * 16 + quad * 4 + r) * 66 + ni * 16 + l16] = c[r];
            }
        }
    }
    __syncthreads();

    // ---- softmax: lane r handles row r; bias + shift-region mask inline ----
    {
        const float scale = 0.17677669529663687f;  // 1/sqrt(32)
        const int r = lane;
        if (r < 49) {
            int ty = r / 7, tx = r - ty * 7;
            int hs = wy * 7 + ty, ws = wx * 7 + tx;
            int ridr = (hs < 49 ? 0 : (hs < 53 ? 1 : 2)) * 3 +
                       (ws < 49 ? 0 : (ws < 53 ? 1 : 2));
            float mx = -3e38f;
            for (int jy = 0; jy < 7; ++jy) {
                int hj = wy * 7 + jy;
                int rr = (hj < 49 ? 0 : (hj < 53 ? 1 : 2)) * 3;
                int brow = (ty - jy + 6) * 13 + 6 + tx;  // - jx gives bias idx
                for (int jx = 0; jx < 7; ++jx) {
                    int j = jy * 7 + jx;
                    int wj = wx * 7 + jx;
                    int rid = rr + (wj < 49 ? 0 : (wj < 53 ? 1 : 2));
                    float s = Ss[r * 66 + j] * scale + table[(brow - jx) * 16 + h];
                    if (rid != ridr) s -= 100.f;
                    Ss[r * 66 + j] = s;
                    mx = fmaxf(mx, s);
                }
            }
            float sum = 0.f;
            for (int j = 0; j < 49; ++j) {
                float e = __expf(Ss[r * 66 + j] - mx);
                sum += e;
                Ps[r * 72 + j] = f2bf(e);       // unnormalized; rescale at write
            }
            for (int j = 49; j < 64; ++j) Ps[r * 72 + j] = 0;
            rinv[r] = 1.f / sum;
        } else {
#pragma unroll
            for (int j = 0; j < 64; ++j) Ps[r * 72 + j] = 0;
            rinv[r] = 0.f;
        }
    }
    __syncthreads();

    // ---- O = P V  (4x2 tiles, K=64 -> 2 MFMA steps) + normalized store ----
    {
#pragma unroll
        for (int mi = 0; mi < 4; mi++) {
#pragma unroll
            for (int ni = 0; ni < 2; ni++) {
                f32x4 c = {0.f, 0.f, 0.f, 0.f};
#pragma unroll
                for (int ks = 0; ks < 2; ks++) {
                    bf16x8 a  = *(const bf16x8*)(Ps  + (mi * 16 + l16) * 72 + ks * 32 + quad * 8);
                    bf16x8 bb = *(const bf16x8*)(Vts + (ni * 16 + l16) * 64 + ks * 32 + quad * 8);
                    c = __builtin_amdgcn_mfma_f32_16x16x32_bf16(a, bb, c, 0, 0, 0);
                }
#pragma unroll
                for (int r = 0; r < 4; r++) {
                    int m = mi * 16 + quad * 4 + r;
                    if (m < 49) {
                        int ty = m / 7, tx = m - ty * 7;
                        int ho = wy * 7 + ty + 3; if (ho >= 56) ho -= 56;
                        int wo = wx * 7 + tx + 3; if (wo >= 56) wo -= 56;
                        size_t tok = ((size_t)b * 56 + ho) * 56 + wo;
                        O[tok * 512 + h * 32 + ni * 16 + l16] = f2bf(c[r] * rinv[m]);
                    }
                }
            }
        }
    }
}

// ---------------------------------------------------------------------------
extern "C" void kernel_launch(void* const* d_in, const int* in_sizes, int n_in,
                              void* d_out, int out_size, void* d_ws, size_t ws_size,
                              hipStream_t stream)
{
    const float* x      = (const float*)d_in[0];
    const float* qkv_w  = (const float*)d_in[1];
    const float* qkv_b  = (const float*)d_in[2];
    const float* proj_w = (const float*)d_in[3];
    const float* proj_b = (const float*)d_in[4];
    const float* table  = (const float*)d_in[5];
    float* out = (float*)d_out;

    const int M  = 16 * 56 * 56;  // 50176 tokens
    const int Cd = 512, C3 = 1536;

    char* ws = (char*)d_ws;
    u16* QKV  = (u16*)ws;                                 // M*1536 bf16 = 154.1 MB
    u16* Xb   = (u16*)(ws + (size_t)M * C3 * 2);          // M*512 bf16 (aliases Obuf)
    u16* Obuf = Xb;                                       // reused after gemm1
    u16* Wt1  = (u16*)(ws + (size_t)M * C3 * 2 + (size_t)M * Cd * 2);
    u16* Wt2  = Wt1 + (size_t)C3 * Cd;

    // x (f32) -> Xb (bf16)
    cvt_f32_bf16<<<(M * Cd) / 2048, 256, 0, stream>>>(x, Xb);

    dim3 tb(32, 32);
    transpose_cvt<<<dim3(C3 / 32, Cd / 32), tb, 0, stream>>>(qkv_w, Wt1, Cd, C3);
    transpose_cvt<<<dim3(Cd / 32, Cd / 32), tb, 0, stream>>>(proj_w, Wt2, Cd, Cd);

    // QKV = Xb @ qkv_w + qkv_b   (original token order; shift fused later)
    gemm_bt<false><<<dim3(C3 / 128, M / 128), 256, 0, stream>>>(
        Xb, Wt1, qkv_b, nullptr, QKV, M, C3, Cd);

    // windowed attention (shift + window partition + reverse fused)
    attn_kernel<<<dim3(1024 * 16), 64, 0, stream>>>(QKV, table, Obuf);

    // out = Obuf @ proj_w + proj_b + x   (residual in f32)
    gemm_bt<true><<<dim3(Cd / 128, M / 128), 256, 0, stream>>>(
        Obuf, Wt2, proj_b, x, out, M, Cd, Cd);
}

// Round 3
// 593.883 us; speedup vs baseline: 1.0708x; 1.0708x over previous
//
#include <hip/hip_runtime.h>
#include <stdint.h>

typedef unsigned short u16;
typedef unsigned int   u32;

typedef __bf16 bf16x8 __attribute__((ext_vector_type(8)));
typedef float  f32x4  __attribute__((ext_vector_type(4)));

__device__ __forceinline__ float bf2f(u16 h) {
    return __uint_as_float(((u32)h) << 16);
}
__device__ __forceinline__ u16 f2bf(float f) {
    u32 u = __float_as_uint(f);
    u += 0x7FFFu + ((u >> 16) & 1u);   // RNE
    return (u16)(u >> 16);
}

#define GLOAD_LDS16(g, l)                                                     \
    __builtin_amdgcn_global_load_lds(                                         \
        (const __attribute__((address_space(1))) void*)(g),                   \
        (__attribute__((address_space(3))) void*)(l), 16, 0, 0)

// ---------------------------------------------------------------------------
// f32 -> bf16 bulk convert, 8 elems/thread
// ---------------------------------------------------------------------------
__global__ __launch_bounds__(256) void cvt_f32_bf16(const float* __restrict__ in,
                                                    u16* __restrict__ out) {
    int i = blockIdx.x * 256 + threadIdx.x;
    const float4* p = (const float4*)in + (size_t)i * 2;
    float4 a = p[0], b = p[1];
    union { u16 s[8]; uint4 v; } o;
    o.s[0] = f2bf(a.x); o.s[1] = f2bf(a.y); o.s[2] = f2bf(a.z); o.s[3] = f2bf(a.w);
    o.s[4] = f2bf(b.x); o.s[5] = f2bf(b.y); o.s[6] = f2bf(b.z); o.s[7] = f2bf(b.w);
    ((uint4*)out)[i] = o.v;
}

// ---------------------------------------------------------------------------
// Transpose+convert W[R][Cc] (f32) -> Wt[Cc][R] (bf16), dims multiple of 32
// ---------------------------------------------------------------------------
__global__ void transpose_cvt(const float* __restrict__ in, u16* __restrict__ out,
                              int R, int Cc) {
    __shared__ float tile[32][33];
    int c0 = blockIdx.x * 32, r0 = blockIdx.y * 32;
    int tx = threadIdx.x, ty = threadIdx.y;
    tile[ty][tx] = in[(size_t)(r0 + ty) * Cc + c0 + tx];
    __syncthreads();
    out[(size_t)(c0 + ty) * R + r0 + tx] = f2bf(tile[tx][ty]);
}

// ---------------------------------------------------------------------------
// Precompute bias+mask, swizzled to the MFMA C-fragment access pattern:
// biasL[cls][h][mi][ni][quad][l16][r] (float4 over r).
// cls = (bottom-edge?2:0)+(right-edge?1:0). cols>=49 get -1e9 (pad vanishes).
// ---------------------------------------------------------------------------
__global__ __launch_bounds__(64) void build_bias(const float* __restrict__ table,
                                                 float* __restrict__ biasL) {
    int cls = blockIdx.x >> 4;
    int h   = blockIdx.x & 15;
    int lane = threadIdx.x;
    int quad = lane >> 4, l16 = lane & 15;
    int eh = cls >> 1, ew = cls & 1;
    float* base = biasL + (size_t)(cls * 16 + h) * 4096;
#pragma unroll
    for (int mi = 0; mi < 4; mi++) {
#pragma unroll
        for (int ni = 0; ni < 4; ni++) {
            float4 v;
            float* vp = &v.x;
#pragma unroll
            for (int r = 0; r < 4; r++) {
                int m = mi * 16 + quad * 4 + r;
                int c = ni * 16 + l16;
                float b;
                if (c >= 49)      b = -1e9f;
                else if (m >= 49) b = 0.f;
                else {
                    int ty = m / 7, tx = m % 7, jy = c / 7, jx = c % 7;
                    b = table[((ty - jy + 6) * 13 + (tx - jx + 6)) * 16 + h];
                    int ridr = (eh ? (ty < 4 ? 1 : 2) : 0) * 3 + (ew ? (tx < 4 ? 1 : 2) : 0);
                    int ridc = (eh ? (jy < 4 ? 1 : 2) : 0) * 3 + (ew ? (jx < 4 ? 1 : 2) : 0);
                    if (ridr != ridc) b -= 100.f;
                }
                vp[r] = b;
            }
            ((float4*)base)[((mi * 4 + ni) * 4 + quad) * 16 + l16] = v;
        }
    }
}

// ---------------------------------------------------------------------------
// C[M][N] = A[M][K] @ Bt[N][K]^T + bias[N] (+ res[M][N]); A,Bt bf16, acc f32.
// 128x128 tile, BK=32, 256 threads (4 waves), m97 structure.
// ---------------------------------------------------------------------------
template <bool OUT_F32>
__global__ __launch_bounds__(256) void gemm_bt(
    const u16* __restrict__ A, const u16* __restrict__ Bt,
    const float* __restrict__ bias, const float* __restrict__ res,
    void* __restrict__ Cout, int M, int N, int K)
{
    __shared__ __align__(16) u16 As[128 * 32];
    __shared__ __align__(16) u16 Bs[128 * 32];

    const int t    = threadIdx.x;
    const int lane = t & 63;
    const int w    = t >> 6;
    const int wm   = w >> 1, wn = w & 1;
    const int quad = lane >> 4, l16 = lane & 15;

    const size_t m0 = (size_t)blockIdx.y * 128;
    const size_t n0 = (size_t)blockIdx.x * 128;

    const u16* Ab = A + m0 * K;
    const u16* Bb = Bt + n0 * K;

    const int rA0 = t >> 2;
    const int cA0 = (t & 3) * 8;

    f32x4 acc[4][4];
    const f32x4 fzero = {0.f, 0.f, 0.f, 0.f};
#pragma unroll
    for (int i = 0; i < 4; i++)
#pragma unroll
        for (int j = 0; j < 4; j++) acc[i][j] = fzero;

    for (int k0 = 0; k0 < K; k0 += 32) {
        const u16* ga0 = Ab + (size_t)rA0 * K + k0 + cA0;
        const u16* ga1 = ga0 + (size_t)64 * K;
        const u16* gb0 = Bb + (size_t)rA0 * K + k0 + cA0;
        const u16* gb1 = gb0 + (size_t)64 * K;
        GLOAD_LDS16(ga0, As + t * 8);
        GLOAD_LDS16(ga1, As + t * 8 + 2048);
        GLOAD_LDS16(gb0, Bs + t * 8);
        GLOAD_LDS16(gb1, Bs + t * 8 + 2048);
        __syncthreads();

        bf16x8 a[4], b[4];
#pragma unroll
        for (int mi = 0; mi < 4; mi++)
            a[mi] = *(const bf16x8*)(As + (wm * 64 + mi * 16 + l16) * 32 + quad * 8);
#pragma unroll
        for (int ni = 0; ni < 4; ni++)
            b[ni] = *(const bf16x8*)(Bs + (wn * 64 + ni * 16 + l16) * 32 + quad * 8);
#pragma unroll
        for (int mi = 0; mi < 4; mi++)
#pragma unroll
            for (int ni = 0; ni < 4; ni++)
                acc[mi][ni] = __builtin_amdgcn_mfma_f32_16x16x32_bf16(
                    a[mi], b[ni], acc[mi][ni], 0, 0, 0);
        __syncthreads();
    }

#pragma unroll
    for (int ni = 0; ni < 4; ni++) {
        const size_t col = n0 + wn * 64 + ni * 16 + l16;
        const float bv = bias[col];
#pragma unroll
        for (int mi = 0; mi < 4; mi++) {
#pragma unroll
            for (int r = 0; r < 4; r++) {
                const size_t row = m0 + wm * 64 + mi * 16 + quad * 4 + r;
                float v = acc[mi][ni][r] + bv;
                if (res) v += res[row * N + col];
                if (OUT_F32) ((float*)Cout)[row * N + col] = v;
                else         ((u16*)Cout)[row * N + col]  = f2bf(v);
            }
        }
    }
}

// ---------------------------------------------------------------------------
// Attention v2: 1 wave per (window, head). Register-resident softmax:
// S stays in MFMA C-frags; row max/sum via shfl_xor over the 16-lane quad
// group; rinv stays in registers (QK C-rows == PV C-rows). Bias+mask+pad
// from precomputed biasL (16 coalesced float4 loads). LDS 14.5 KB:
// Ps aliases Qs/Ks after the QK phase; strides padded (40/72) for banks.
// ---------------------------------------------------------------------------
__global__ __launch_bounds__(64) void attn_kernel(
    const u16* __restrict__ qkv, const float* __restrict__ biasL,
    u16* __restrict__ O)
{
    __shared__ __align__(16) char smem[14848];
    u16* Qs  = (u16*)smem;              // [64][40]
    u16* Ks  = (u16*)(smem + 5120);     // [64][40]
    u16* Ps  = (u16*)smem;              // [64][72]  (aliases Qs/Ks)
    u16* Vts = (u16*)(smem + 10240);    // [32][72]

    const int wid = blockIdx.x >> 4;
    const int h   = blockIdx.x & 15;
    const int b   = wid >> 6;
    const int wy  = (wid >> 3) & 7;
    const int wx  = wid & 7;
    const int cls = ((wy == 7) ? 2 : 0) + ((wx == 7) ? 1 : 0);
    const int lane = threadIdx.x;
    const int quad = lane >> 4, l16 = lane & 15;

    // ---- gather Q,K,V (49 tokens x 32 dims), zero-pad to 64 ----
    if (lane < 49) {
        int ty = lane / 7, tx = lane - ty * 7;
        int ho = wy * 7 + ty + 3; if (ho >= 56) ho -= 56;
        int wo = wx * 7 + tx + 3; if (wo >= 56) wo -= 56;
        size_t tok = ((size_t)b * 56 + ho) * 56 + wo;
        const u16* base = qkv + tok * 1536 + h * 32;
        uint4* qd = (uint4*)(Qs + lane * 40);
        const uint4* qs = (const uint4*)base;
        qd[0] = qs[0]; qd[1] = qs[1]; qd[2] = qs[2]; qd[3] = qs[3];
        uint4* kd = (uint4*)(Ks + lane * 40);
        const uint4* ks = (const uint4*)(base + 512);
        kd[0] = ks[0]; kd[1] = ks[1]; kd[2] = ks[2]; kd[3] = ks[3];
        union { uint4 u4[4]; u16 s[32]; } vb;
        const uint4* vs = (const uint4*)(base + 1024);
        vb.u4[0] = vs[0]; vb.u4[1] = vs[1]; vb.u4[2] = vs[2]; vb.u4[3] = vs[3];
#pragma unroll
        for (int d = 0; d < 32; d++) Vts[d * 72 + lane] = vb.s[d];
    } else {
        uint4 z = make_uint4(0, 0, 0, 0);
        uint4* qd = (uint4*)(Qs + lane * 40);
        qd[0] = z; qd[1] = z; qd[2] = z; qd[3] = z;
        uint4* kd = (uint4*)(Ks + lane * 40);
        kd[0] = z; kd[1] = z; kd[2] = z; kd[3] = z;
#pragma unroll
        for (int d = 0; d < 32; d++) Vts[d * 72 + lane] = 0;
    }
    __syncthreads();

    // ---- S = Q K^T  (4x4 tiles, K=32 -> one MFMA each), stays in regs ----
    f32x4 acc[4][4];
    {
        bf16x8 a[4], bb[4];
#pragma unroll
        for (int i = 0; i < 4; i++) {
            a[i]  = *(const bf16x8*)(Qs + (i * 16 + l16) * 40 + quad * 8);
            bb[i] = *(const bf16x8*)(Ks + (i * 16 + l16) * 40 + quad * 8);
        }
        const f32x4 fz = {0.f, 0.f, 0.f, 0.f};
#pragma unroll
        for (int mi = 0; mi < 4; mi++)
#pragma unroll
            for (int ni = 0; ni < 4; ni++)
                acc[mi][ni] = __builtin_amdgcn_mfma_f32_16x16x32_bf16(
                    a[mi], bb[ni], fz, 0, 0, 0);
    }

    // ---- s = S*scale + bias(+mask,+pad) ----
    {
        const float scale = 0.17677669529663687f;  // 1/sqrt(32)
        const float* bp = biasL + (size_t)(cls * 16 + h) * 4096;
#pragma unroll
        for (int mi = 0; mi < 4; mi++)
#pragma unroll
            for (int ni = 0; ni < 4; ni++) {
                float4 bv = ((const float4*)bp)[((mi * 4 + ni) * 4 + quad) * 16 + l16];
                const float* bvp = &bv.x;
#pragma unroll
                for (int r = 0; r < 4; r++)
                    acc[mi][ni][r] = acc[mi][ni][r] * scale + bvp[r];
            }
    }

    // ---- row max / exp / row sum, all in registers + shfl butterflies ----
    float rinv[4][4];
    {
        float mx[4][4];
#pragma unroll
        for (int mi = 0; mi < 4; mi++)
#pragma unroll
            for (int r = 0; r < 4; r++) {
                float m0 = fmaxf(fmaxf(acc[mi][0][r], acc[mi][1][r]),
                                 fmaxf(acc[mi][2][r], acc[mi][3][r]));
                m0 = fmaxf(m0, __shfl_xor(m0, 1, 64));
                m0 = fmaxf(m0, __shfl_xor(m0, 2, 64));
                m0 = fmaxf(m0, __shfl_xor(m0, 4, 64));
                m0 = fmaxf(m0, __shfl_xor(m0, 8, 64));
                mx[mi][r] = m0;
            }
#pragma unroll
        for (int mi = 0; mi < 4; mi++)
#pragma unroll
            for (int r = 0; r < 4; r++) {
                float e0 = __expf(acc[mi][0][r] - mx[mi][r]);
                float e1 = __expf(acc[mi][1][r] - mx[mi][r]);
                float e2 = __expf(acc[mi][2][r] - mx[mi][r]);
                float e3 = __expf(acc[mi][3][r] - mx[mi][r]);
                acc[mi][0][r] = e0; acc[mi][1][r] = e1;
                acc[mi][2][r] = e2; acc[mi][3][r] = e3;
                float s0 = (e0 + e1) + (e2 + e3);
                s0 += __shfl_xor(s0, 1, 64);
                s0 += __shfl_xor(s0, 2, 64);
                s0 += __shfl_xor(s0, 4, 64);
                s0 += __shfl_xor(s0, 8, 64);
                rinv[mi][r] = __builtin_amdgcn_rcpf(s0);
            }
    }

    // ---- P (bf16, unnormalized) into LDS (C-layout), aliasing Qs/Ks ----
    __syncthreads();   // ensure Q/K frag reads drained before overwrite
#pragma unroll
    for (int mi = 0; mi < 4; mi++)
#pragma unroll
        for (int ni = 0; ni < 4; ni++)
#pragma unroll
            for (int r = 0; r < 4; r++)
                Ps[(mi * 16 + quad * 4 + r) * 72 + ni * 16 + l16] =
                    f2bf(acc[mi][ni][r]);
    __syncthreads();

    // ---- O = P V  (4x2 tiles, K=64 -> 2 MFMA steps), normalized store ----
#pragma unroll
    for (int mi = 0; mi < 4; mi++) {
        f32x4 c0 = {0.f, 0.f, 0.f, 0.f}, c1 = {0.f, 0.f, 0.f, 0.f};
#pragma unroll
        for (int ks = 0; ks < 2; ks++) {
            bf16x8 a = *(const bf16x8*)(Ps + (mi * 16 + l16) * 72 + ks * 32 + quad * 8);
            bf16x8 b0 = *(const bf16x8*)(Vts + l16 * 72 + ks * 32 + quad * 8);
            bf16x8 b1 = *(const bf16x8*)(Vts + (16 + l16) * 72 + ks * 32 + quad * 8);
            c0 = __builtin_amdgcn_mfma_f32_16x16x32_bf16(a, b0, c0, 0, 0, 0);
            c1 = __builtin_amdgcn_mfma_f32_16x16x32_bf16(a, b1, c1, 0, 0, 0);
        }
#pragma unroll
        for (int r = 0; r < 4; r++) {
            int m = mi * 16 + quad * 4 + r;
            if (m < 49) {
                int ty = m / 7, tx = m - ty * 7;
                int ho = wy * 7 + ty + 3; if (ho >= 56) ho -= 56;
                int wo = wx * 7 + tx + 3; if (wo >= 56) wo -= 56;
                size_t tok = ((size_t)b * 56 + ho) * 56 + wo;
                u16* op = O + tok * 512 + h * 32 + l16;
                op[0]  = f2bf(c0[r] * rinv[mi][r]);
                op[16] = f2bf(c1[r] * rinv[mi][r]);
            }
        }
    }
}

// ---------------------------------------------------------------------------
extern "C" void kernel_launch(void* const* d_in, const int* in_sizes, int n_in,
                              void* d_out, int out_size, void* d_ws, size_t ws_size,
                              hipStream_t stream)
{
    const float* x      = (const float*)d_in[0];
    const float* qkv_w  = (const float*)d_in[1];
    const float* qkv_b  = (const float*)d_in[2];
    const float* proj_w = (const float*)d_in[3];
    const float* proj_b = (const float*)d_in[4];
    const float* table  = (const float*)d_in[5];
    float* out = (float*)d_out;

    const int M  = 16 * 56 * 56;  // 50176 tokens
    const int Cd = 512, C3 = 1536;

    char* ws = (char*)d_ws;
    u16* QKV  = (u16*)ws;                                 // M*1536 bf16
    u16* Xb   = (u16*)(ws + (size_t)M * C3 * 2);          // M*512 bf16 (= Obuf)
    u16* Obuf = Xb;                                       // reused after gemm1
    u16* Wt1  = (u16*)(ws + (size_t)M * C3 * 2 + (size_t)M * Cd * 2);
    u16* Wt2  = Wt1 + (size_t)C3 * Cd;
    float* biasL = (float*)Wt1;  // 4*16*4096 f32 = 1 MB, aliases Wt1 (dead
                                 // after gemm1); built after gemm1.

    cvt_f32_bf16<<<(M * Cd) / 2048, 256, 0, stream>>>(x, Xb);

    dim3 tb(32, 32);
    transpose_cvt<<<dim3(C3 / 32, Cd / 32), tb, 0, stream>>>(qkv_w, Wt1, Cd, C3);
    transpose_cvt<<<dim3(Cd / 32, Cd / 32), tb, 0, stream>>>(proj_w, Wt2, Cd, Cd);

    // QKV = Xb @ qkv_w + qkv_b
    gemm_bt<false><<<dim3(C3 / 128, M / 128), 256, 0, stream>>>(
        Xb, Wt1, qkv_b, nullptr, QKV, M, C3, Cd);

    // bias+mask tables (into Wt1's space — Wt1 is dead now)
    build_bias<<<dim3(64), 64, 0, stream>>>(table, biasL);

    // windowed attention (shift + partition + reverse fused)
    attn_kernel<<<dim3(1024 * 16), 64, 0, stream>>>(QKV, biasL, Obuf);

    // out = Obuf @ proj_w + proj_b + x  (residual f32)
    gemm_bt<true><<<dim3(Cd / 128, M / 128), 256, 0, stream>>>(
        Obuf, Wt2, proj_b, x, out, M, Cd, Cd);
}

// Round 4
// 479.068 us; speedup vs baseline: 1.3275x; 1.2397x over previous
//
#include <hip/hip_runtime.h>
#include <stdint.h>

typedef unsigned short u16;
typedef unsigned int   u32;

typedef __bf16 bf16x8 __attribute__((ext_vector_type(8)));
typedef float  f32x4  __attribute__((ext_vector_type(4)));

__device__ __forceinline__ float bf2f(u16 h) {
    return __uint_as_float(((u32)h) << 16);
}
__device__ __forceinline__ u16 f2bf(float f) {
    u32 u = __float_as_uint(f);
    u += 0x7FFFu + ((u >> 16) & 1u);   // RNE
    return (u16)(u >> 16);
}

#define GLOAD_LDS16(g, l)                                                     \
    __builtin_amdgcn_global_load_lds(                                         \
        (const __attribute__((address_space(1))) void*)(g),                   \
        (__attribute__((address_space(3))) void*)(l), 16, 0, 0)

// ---------------------------------------------------------------------------
// f32 -> bf16 bulk convert, 8 elems/thread
// ---------------------------------------------------------------------------
__global__ __launch_bounds__(256) void cvt_f32_bf16(const float* __restrict__ in,
                                                    u16* __restrict__ out) {
    int i = blockIdx.x * 256 + threadIdx.x;
    const float4* p = (const float4*)in + (size_t)i * 2;
    float4 a = p[0], b = p[1];
    union { u16 s[8]; uint4 v; } o;
    o.s[0] = f2bf(a.x); o.s[1] = f2bf(a.y); o.s[2] = f2bf(a.z); o.s[3] = f2bf(a.w);
    o.s[4] = f2bf(b.x); o.s[5] = f2bf(b.y); o.s[6] = f2bf(b.z); o.s[7] = f2bf(b.w);
    ((uint4*)out)[i] = o.v;
}

// ---------------------------------------------------------------------------
// Transpose+convert W[R][Cc] (f32) -> Wt[Cc][R] (bf16), dims multiple of 32
// ---------------------------------------------------------------------------
__global__ void transpose_cvt(const float* __restrict__ in, u16* __restrict__ out,
                              int R, int Cc) {
    __shared__ float tile[32][33];
    int c0 = blockIdx.x * 32, r0 = blockIdx.y * 32;
    int tx = threadIdx.x, ty = threadIdx.y;
    tile[ty][tx] = in[(size_t)(r0 + ty) * Cc + c0 + tx];
    __syncthreads();
    out[(size_t)(c0 + ty) * R + r0 + tx] = f2bf(tile[tx][ty]);
}

// ---------------------------------------------------------------------------
// Precompute bias+mask, swizzled to the MFMA C-fragment access pattern:
// biasL[cls][h][mi][ni][quad][l16][r] (float4 over r).
// cls = (bottom-edge?2:0)+(right-edge?1:0). cols>=49 get -1e9 (pad vanishes).
// ---------------------------------------------------------------------------
__global__ __launch_bounds__(64) void build_bias(const float* __restrict__ table,
                                                 float* __restrict__ biasL) {
    int cls = blockIdx.x >> 4;
    int h   = blockIdx.x & 15;
    int lane = threadIdx.x;
    int quad = lane >> 4, l16 = lane & 15;
    int eh = cls >> 1, ew = cls & 1;
    float* base = biasL + (size_t)(cls * 16 + h) * 4096;
#pragma unroll
    for (int mi = 0; mi < 4; mi++) {
#pragma unroll
        for (int ni = 0; ni < 4; ni++) {
            float4 v;
            float* vp = &v.x;
#pragma unroll
            for (int r = 0; r < 4; r++) {
                int m = mi * 16 + quad * 4 + r;
                int c = ni * 16 + l16;
                float b;
                if (c >= 49)      b = -1e9f;
                else if (m >= 49) b = 0.f;
                else {
                    int ty = m / 7, tx = m % 7, jy = c / 7, jx = c % 7;
                    b = table[((ty - jy + 6) * 13 + (tx - jx + 6)) * 16 + h];
                    int ridr = (eh ? (ty < 4 ? 1 : 2) : 0) * 3 + (ew ? (tx < 4 ? 1 : 2) : 0);
                    int ridc = (eh ? (jy < 4 ? 1 : 2) : 0) * 3 + (ew ? (jx < 4 ? 1 : 2) : 0);
                    if (ridr != ridc) b -= 100.f;
                }
                vp[r] = b;
            }
            ((float4*)base)[((mi * 4 + ni) * 4 + quad) * 16 + l16] = v;
        }
    }
}

// ---------------------------------------------------------------------------
// C[M][N] = A[M][K] @ Bt[N][K]^T + bias[N] (+ res[M][N]); A,Bt bf16, acc f32.
// 128x128 tile, BK=32, 256 threads (4 waves), m97 K-loop. Epilogue goes
// through a per-wave [16][68] f32 LDS scratch (aliases As/Bs) so global
// stores are row-contiguous 16B/8B vectors instead of 64 scattered scalars.
// ---------------------------------------------------------------------------
template <bool OUT_F32>
__global__ __launch_bounds__(256) void gemm_bt(
    const u16* __restrict__ A, const u16* __restrict__ Bt,
    const float* __restrict__ bias, const float* __restrict__ res,
    void* __restrict__ Cout, int M, int N, int K)
{
    __shared__ __align__(16) char smem[17408];   // K-loop: As 8K | Bs 8K
    u16* As = (u16*)smem;                        // epilogue: 4 x 4352B scratch
    u16* Bs = (u16*)(smem + 8192);

    const int t    = threadIdx.x;
    const int lane = t & 63;
    const int w    = t >> 6;
    const int wm   = w >> 1, wn = w & 1;
    const int quad = lane >> 4, l16 = lane & 15;

    const size_t m0 = (size_t)blockIdx.y * 128;
    const size_t n0 = (size_t)blockIdx.x * 128;

    const u16* Ab = A + m0 * K;
    const u16* Bb = Bt + n0 * K;

    const int rA0 = t >> 2;
    const int cA0 = (t & 3) * 8;

    f32x4 acc[4][4];
    const f32x4 fzero = {0.f, 0.f, 0.f, 0.f};
#pragma unroll
    for (int i = 0; i < 4; i++)
#pragma unroll
        for (int j = 0; j < 4; j++) acc[i][j] = fzero;

    for (int k0 = 0; k0 < K; k0 += 32) {
        const u16* ga0 = Ab + (size_t)rA0 * K + k0 + cA0;
        const u16* ga1 = ga0 + (size_t)64 * K;
        const u16* gb0 = Bb + (size_t)rA0 * K + k0 + cA0;
        const u16* gb1 = gb0 + (size_t)64 * K;
        GLOAD_LDS16(ga0, As + t * 8);
        GLOAD_LDS16(ga1, As + t * 8 + 2048);
        GLOAD_LDS16(gb0, Bs + t * 8);
        GLOAD_LDS16(gb1, Bs + t * 8 + 2048);
        __syncthreads();

        bf16x8 a[4], b[4];
#pragma unroll
        for (int mi = 0; mi < 4; mi++)
            a[mi] = *(const bf16x8*)(As + (wm * 64 + mi * 16 + l16) * 32 + quad * 8);
#pragma unroll
        for (int ni = 0; ni < 4; ni++)
            b[ni] = *(const bf16x8*)(Bs + (wn * 64 + ni * 16 + l16) * 32 + quad * 8);
#pragma unroll
        for (int mi = 0; mi < 4; mi++)
#pragma unroll
            for (int ni = 0; ni < 4; ni++)
                acc[mi][ni] = __builtin_amdgcn_mfma_f32_16x16x32_bf16(
                    a[mi], b[ni], acc[mi][ni], 0, 0, 0);
        __syncthreads();
    }

    // ---- epilogue: per-wave LDS transpose -> vectorized stores ----
    float* scr = (float*)smem + w * 1088;        // [16][68] f32 per wave
    float bv[4];
#pragma unroll
    for (int ni = 0; ni < 4; ni++)
        bv[ni] = bias[n0 + wn * 64 + ni * 16 + l16];

    const size_t colb = n0 + wn * 64 + quad * 16;
#pragma unroll
    for (int mi = 0; mi < 4; mi++) {
#pragma unroll
        for (int ni = 0; ni < 4; ni++)
#pragma unroll
            for (int r = 0; r < 4; r++)
                scr[(quad * 4 + r) * 68 + ni * 16 + l16] = acc[mi][ni][r] + bv[ni];
        __builtin_amdgcn_s_waitcnt(0);   // drain ds writes (per-wave region)

        const size_t row = m0 + wm * 64 + mi * 16 + l16;
        const float4* sp = (const float4*)(scr + l16 * 68 + quad * 16);
        float4 v0 = sp[0], v1 = sp[1], v2 = sp[2], v3 = sp[3];

        if (OUT_F32) {
            const float4* rp = (const float4*)(res + row * N + colb);
            float4 r0 = rp[0], r1 = rp[1], r2 = rp[2], r3 = rp[3];
            v0.x += r0.x; v0.y += r0.y; v0.z += r0.z; v0.w += r0.w;
            v1.x += r1.x; v1.y += r1.y; v1.z += r1.z; v1.w += r1.w;
            v2.x += r2.x; v2.y += r2.y; v2.z += r2.z; v2.w += r2.w;
            v3.x += r3.x; v3.y += r3.y; v3.z += r3.z; v3.w += r3.w;
            float4* op = (float4*)((float*)Cout + row * N + colb);
            op[0] = v0; op[1] = v1; op[2] = v2; op[3] = v3;
        } else {
            union { u16 s[8]; uint4 q; } p0, p1;
            p0.s[0] = f2bf(v0.x); p0.s[1] = f2bf(v0.y); p0.s[2] = f2bf(v0.z); p0.s[3] = f2bf(v0.w);
            p0.s[4] = f2bf(v1.x); p0.s[5] = f2bf(v1.y); p0.s[6] = f2bf(v1.z); p0.s[7] = f2bf(v1.w);
            p1.s[0] = f2bf(v2.x); p1.s[1] = f2bf(v2.y); p1.s[2] = f2bf(v2.z); p1.s[3] = f2bf(v2.w);
            p1.s[4] = f2bf(v3.x); p1.s[5] = f2bf(v3.y); p1.s[6] = f2bf(v3.z); p1.s[7] = f2bf(v3.w);
            uint4* op = (uint4*)((u16*)Cout + row * N + colb);
            op[0] = p0.q; op[1] = p1.q;
        }
        __builtin_amdgcn_s_waitcnt(0);   // scratch reads done before next mi
    }
}

// ---------------------------------------------------------------------------
// Attention v3: 1 wave per (window, head). Q/K fragments loaded directly
// global->VGPR (16x16x32 A/B fragment == 16B row slice). Rows/cols >=49
// clamp the token index to 48; the -1e9 pad bias kills cols>=49 and garbage
// rows are never stored. Register softmax; P through LDS (C->A layout).
// ---------------------------------------------------------------------------
__global__ __launch_bounds__(64) void attn_kernel(
    const u16* __restrict__ qkv, const float* __restrict__ biasL,
    u16* __restrict__ O)
{
    __shared__ __align__(16) u16 Ps[64 * 72];   // 9216 B
    __shared__ __align__(16) u16 Vts[32 * 72];  // 4608 B

    const int wid = blockIdx.x >> 4;
    const int h   = blockIdx.x & 15;
    const int b   = wid >> 6;
    const int wy  = (wid >> 3) & 7;
    const int wx  = wid & 7;
    const int cls = ((wy == 7) ? 2 : 0) + ((wx == 7) ? 1 : 0);
    const int lane = threadIdx.x;
    const int quad = lane >> 4, l16 = lane & 15;

    // token index (original layout) for window position m, clamped to 48
    auto tokOf = [&](int m) -> size_t {
        int tt = m < 49 ? m : 48;
        int ty = tt / 7, tx = tt - ty * 7;
        int ho = wy * 7 + ty + 3; if (ho >= 56) ho -= 56;
        int wo = wx * 7 + tx + 3; if (wo >= 56) wo -= 56;
        return ((size_t)b * 56 + ho) * 56 + wo;
    };

    // ---- V gather -> Vts[dim][token] (token = lane, clamped) ----
    {
        size_t tok = tokOf(lane);
        const uint4* vs = (const uint4*)(qkv + tok * 1536 + 1024 + h * 32);
        union { uint4 u4[4]; u16 s[32]; } vb;
        vb.u4[0] = vs[0]; vb.u4[1] = vs[1]; vb.u4[2] = vs[2]; vb.u4[3] = vs[3];
#pragma unroll
        for (int d = 0; d < 32; d++) Vts[d * 72 + lane] = vb.s[d];
    }

    // ---- Q/K fragments directly from global ----
    bf16x8 aq[4], bk[4];
#pragma unroll
    for (int i = 0; i < 4; i++) {
        size_t tok = tokOf(i * 16 + l16);
        const u16* base = qkv + tok * 1536 + h * 32 + quad * 8;
        aq[i] = *(const bf16x8*)base;
        bk[i] = *(const bf16x8*)(base + 512);
    }

    // ---- S = Q K^T (regs) ----
    f32x4 acc[4][4];
    {
        const f32x4 fz = {0.f, 0.f, 0.f, 0.f};
#pragma unroll
        for (int mi = 0; mi < 4; mi++)
#pragma unroll
            for (int ni = 0; ni < 4; ni++)
                acc[mi][ni] = __builtin_amdgcn_mfma_f32_16x16x32_bf16(
                    aq[mi], bk[ni], fz, 0, 0, 0);
    }

    // ---- s = S*scale + bias(+mask,+pad) ----
    {
        const float scale = 0.17677669529663687f;  // 1/sqrt(32)
        const float* bp = biasL + (size_t)(cls * 16 + h) * 4096;
#pragma unroll
        for (int mi = 0; mi < 4; mi++)
#pragma unroll
            for (int ni = 0; ni < 4; ni++) {
                float4 bvv = ((const float4*)bp)[((mi * 4 + ni) * 4 + quad) * 16 + l16];
                const float* bvp = &bvv.x;
#pragma unroll
                for (int r = 0; r < 4; r++)
                    acc[mi][ni][r] = acc[mi][ni][r] * scale + bvp[r];
            }
    }

    // ---- row max / exp / row sum (register + shfl butterflies) ----
    float rinv[4][4];
    {
#pragma unroll
        for (int mi = 0; mi < 4; mi++)
#pragma unroll
            for (int r = 0; r < 4; r++) {
                float m0 = fmaxf(fmaxf(acc[mi][0][r], acc[mi][1][r]),
                                 fmaxf(acc[mi][2][r], acc[mi][3][r]));
                m0 = fmaxf(m0, __shfl_xor(m0, 1, 64));
                m0 = fmaxf(m0, __shfl_xor(m0, 2, 64));
                m0 = fmaxf(m0, __shfl_xor(m0, 4, 64));
                m0 = fmaxf(m0, __shfl_xor(m0, 8, 64));
                float e0 = __expf(acc[mi][0][r] - m0);
                float e1 = __expf(acc[mi][1][r] - m0);
                float e2 = __expf(acc[mi][2][r] - m0);
                float e3 = __expf(acc[mi][3][r] - m0);
                acc[mi][0][r] = e0; acc[mi][1][r] = e1;
                acc[mi][2][r] = e2; acc[mi][3][r] = e3;
                float s0 = (e0 + e1) + (e2 + e3);
                s0 += __shfl_xor(s0, 1, 64);
                s0 += __shfl_xor(s0, 2, 64);
                s0 += __shfl_xor(s0, 4, 64);
                s0 += __shfl_xor(s0, 8, 64);
                rinv[mi][r] = __builtin_amdgcn_rcpf(s0);
            }
    }

    // ---- P (bf16, unnormalized) into LDS in C-layout ----
#pragma unroll
    for (int mi = 0; mi < 4; mi++)
#pragma unroll
        for (int ni = 0; ni < 4; ni++)
#pragma unroll
            for (int r = 0; r < 4; r++)
                Ps[(mi * 16 + quad * 4 + r) * 72 + ni * 16 + l16] =
                    f2bf(acc[mi][ni][r]);
    __syncthreads();

    // ---- O = P V (4x2 tiles, K=64 -> 2 MFMA steps), normalized store ----
#pragma unroll
    for (int mi = 0; mi < 4; mi++) {
        f32x4 c0 = {0.f, 0.f, 0.f, 0.f}, c1 = {0.f, 0.f, 0.f, 0.f};
#pragma unroll
        for (int ks = 0; ks < 2; ks++) {
            bf16x8 a = *(const bf16x8*)(Ps + (mi * 16 + l16) * 72 + ks * 32 + quad * 8);
            bf16x8 b0 = *(const bf16x8*)(Vts + l16 * 72 + ks * 32 + quad * 8);
            bf16x8 b1 = *(const bf16x8*)(Vts + (16 + l16) * 72 + ks * 32 + quad * 8);
            c0 = __builtin_amdgcn_mfma_f32_16x16x32_bf16(a, b0, c0, 0, 0, 0);
            c1 = __builtin_amdgcn_mfma_f32_16x16x32_bf16(a, b1, c1, 0, 0, 0);
        }
#pragma unroll
        for (int r = 0; r < 4; r++) {
            int m = mi * 16 + quad * 4 + r;
            if (m < 49) {
                int ty = m / 7, tx = m - ty * 7;
                int ho = wy * 7 + ty + 3; if (ho >= 56) ho -= 56;
                int wo = wx * 7 + tx + 3; if (wo >= 56) wo -= 56;
                size_t tok = ((size_t)b * 56 + ho) * 56 + wo;
                u16* op = O + tok * 512 + h * 32 + l16;
                op[0]  = f2bf(c0[r] * rinv[mi][r]);
                op[16] = f2bf(c1[r] * rinv[mi][r]);
            }
        }
    }
}

// ---------------------------------------------------------------------------
extern "C" void kernel_launch(void* const* d_in, const int* in_sizes, int n_in,
                              void* d_out, int out_size, void* d_ws, size_t ws_size,
                              hipStream_t stream)
{
    const float* x      = (const float*)d_in[0];
    const float* qkv_w  = (const float*)d_in[1];
    const float* qkv_b  = (const float*)d_in[2];
    const float* proj_w = (const float*)d_in[3];
    const float* proj_b = (const float*)d_in[4];
    const float* table  = (const float*)d_in[5];
    float* out = (float*)d_out;

    const int M  = 16 * 56 * 56;  // 50176 tokens
    const int Cd = 512, C3 = 1536;

    char* ws = (char*)d_ws;
    u16* QKV  = (u16*)ws;                                 // M*1536 bf16
    u16* Xb   = (u16*)(ws + (size_t)M * C3 * 2);          // M*512 bf16 (= Obuf)
    u16* Obuf = Xb;                                       // reused after gemm1
    u16* Wt1  = (u16*)(ws + (size_t)M * C3 * 2 + (size_t)M * Cd * 2);
    u16* Wt2  = Wt1 + (size_t)C3 * Cd;
    float* biasL = (float*)Wt1;  // 1 MB, aliases Wt1 (dead after gemm1)

    cvt_f32_bf16<<<(M * Cd) / 2048, 256, 0, stream>>>(x, Xb);

    dim3 tb(32, 32);
    transpose_cvt<<<dim3(C3 / 32, Cd / 32), tb, 0, stream>>>(qkv_w, Wt1, Cd, C3);
    transpose_cvt<<<dim3(Cd / 32, Cd / 32), tb, 0, stream>>>(proj_w, Wt2, Cd, Cd);

    // QKV = Xb @ qkv_w + qkv_b
    gemm_bt<false><<<dim3(C3 / 128, M / 128), 256, 0, stream>>>(
        Xb, Wt1, qkv_b, nullptr, QKV, M, C3, Cd);

    // bias+mask tables (into Wt1's space — Wt1 dead now)
    build_bias<<<dim3(64), 64, 0, stream>>>(table, biasL);

    // windowed attention (shift + partition + reverse fused)
    attn_kernel<<<dim3(1024 * 16), 64, 0, stream>>>(QKV, biasL, Obuf);

    // out = Obuf @ proj_w + proj_b + x  (residual f32)
    gemm_bt<true><<<dim3(Cd / 128, M / 128), 256, 0, stream>>>(
        Obuf, Wt2, proj_b, x, out, M, Cd, Cd);
}